// Round 10
// baseline (10965.336 us; speedup 1.0000x reference)
//
#include <hip/hip_runtime.h>
#include <stdint.h>

#define TT 2048
#define BB 32
#define II 512
#define HH 512
#define BHE (BB * HH)      // 16384
#define NT 512             // 8 waves per WG
#define RING 16            // y0 cross-layer ring slots
#define XCC_GETREG_IMM (20 | (31 << 11))   // hwreg(HW_REG_XCC_ID=20, off 0, size 32)

typedef unsigned short u16;
typedef unsigned int u32;
typedef __attribute__((ext_vector_type(8))) short bf16x8;
typedef __attribute__((ext_vector_type(4))) float f32x4;

__device__ __forceinline__ u16 f2bf(float f) {
  u32 u = __float_as_uint(f);
  return (u16)((u + 0x7fffu + ((u >> 16) & 1u)) >> 16);  // RNE
}
__device__ __forceinline__ float bf2f(u16 h) { return __uint_as_float(((u32)h) << 16); }
__device__ __forceinline__ float sigm(float x) { return 1.f / (1.f + __expf(-x)); }
__device__ __forceinline__ float tanh_(float x) {
  float xc = fminf(fmaxf(x, -15.f), 15.f);
  float e = __expf(-2.f * xc);
  return (1.f - e) / (1.f + e);
}

// Data-path scope primitives. L2 (same-XCD): sc0. SYS (cross-XCD via MALL): sc0 sc1.
// (R8-proven: pods are XCD-local; L2-scope pod DATA communication is correct --
// data lines turn over in L1 every step. Flags must NOT use plain sc0 loads:
// a hot flag line can sit stale in L1 forever (R7/R9 deadlocks).)
__device__ __forceinline__ bf16x8 ld128_l2(const u16* p) {
  bf16x8 r; asm volatile("global_load_dwordx4 %0, %1, off sc0" : "=v"(r) : "v"(p) : "memory"); return r;
}
__device__ __forceinline__ bf16x8 ld128_sys(const u16* p) {
  bf16x8 r; asm volatile("global_load_dwordx4 %0, %1, off sc0 sc1" : "=v"(r) : "v"(p) : "memory"); return r;
}
__device__ __forceinline__ void st16_l2(u16* p, u16 v) {
  u32 vv = v; asm volatile("global_store_short %0, %1, off sc0" :: "v"(p), "v"(vv) : "memory");
}
__device__ __forceinline__ void st16_sys(u16* p, u16 v) {
  u32 vv = v; asm volatile("global_store_short %0, %1, off sc0 sc1" :: "v"(p), "v"(vv) : "memory");
}
// L2-scope flag primitives via ATOMICS (execute at L2, structurally bypass L1).
// Poll: atomic add-0 with return (sc0 = return-old), s_waitcnt EMBEDDED (R6 lesson).
__device__ __forceinline__ u32 at_add0_ret_l2(u32* p) {
  u32 r, z = 0;
  asm volatile("global_atomic_add %0, %1, %2, off sc0\n\ts_waitcnt vmcnt(0)"
               : "=v"(r) : "v"(p), "v"(z) : "memory");
  return r;
}
__device__ __forceinline__ void at_add1_l2(u32* p) {
  u32 one = 1;
  asm volatile("global_atomic_add %0, %1, off" :: "v"(p), "v"(one) : "memory");
}

#define SCHED0() __builtin_amdgcn_sched_barrier(0)

// ---- prep: x fp32 -> 2-limb bf16 ----
__global__ void k_cvt_x(const float* __restrict__ x, u16* __restrict__ xh, u16* __restrict__ xl) {
  const long n = (long)TT * BB * II;
  long i = ((long)blockIdx.x * 256 + threadIdx.x) * 4;
  const long stride = (long)gridDim.x * 256 * 4;
  for (; i < n; i += stride) {
    float4 v = *(const float4*)(x + i);
    ushort4 h, l;
    h.x = f2bf(v.x); l.x = f2bf(v.x - bf2f(h.x));
    h.y = f2bf(v.y); l.y = f2bf(v.y - bf2f(h.y));
    h.z = f2bf(v.z); l.z = f2bf(v.z - bf2f(h.z));
    h.w = f2bf(v.w); l.w = f2bf(v.w - bf2f(h.w));
    *(ushort4*)(xh + i) = h;
    *(ushort4*)(xl + i) = l;
  }
}

// ---- prep: gate-permuted 2-limb weights. rr = hidx*4+q, srow = q*512+hidx ----
__global__ void k_build_w(const float* __restrict__ Wih0, const float* __restrict__ Whh0,
                          const float* __restrict__ bih0, const float* __restrict__ bhh0,
                          const float* __restrict__ Wih1, const float* __restrict__ Whh1,
                          const float* __restrict__ bih1, const float* __restrict__ bhh1,
                          u16* __restrict__ WH0, u16* __restrict__ WL0,
                          u16* __restrict__ WH1, u16* __restrict__ WL1,
                          float* __restrict__ bsum0, float* __restrict__ bsum1) {
  const int rr = blockIdx.x & 2047;
  const int layer = blockIdx.x >> 11;
  const float* Wih = layer ? Wih1 : Wih0;
  const float* Whh = layer ? Whh1 : Whh0;
  u16* WH = (layer ? WH1 : WH0) + ((size_t)rr << 10);
  u16* WL = (layer ? WL1 : WL0) + ((size_t)rr << 10);
  const int hidx = rr >> 2, q = rr & 3;
  const int srow = q * HH + hidx;
  const float* si = Wih + (size_t)srow * II;
  const float* sh = Whh + (size_t)srow * HH;
  for (int k = threadIdx.x; k < 512; k += 256) {
    float wi = si[k]; u16 a = f2bf(wi); WH[k] = a;       WL[k] = f2bf(wi - bf2f(a));
    float wh = sh[k]; u16 b = f2bf(wh); WH[512 + k] = b; WL[512 + k] = f2bf(wh - bf2f(b));
  }
  if (threadIdx.x == 0)
    (layer ? bsum1 : bsum0)[rr] = (layer ? bih1 : bih0)[srow] + (layer ? bhh1 : bhh0)[srow];
}

// ---- prep: h0 -> per-pod hloc slot0 (2-limb), zero control block ----
// hloc layout: [pid][slot2][bl16][hidx512], pid = layer*2 + batchhalf
__global__ void k_init(const float* __restrict__ h0,
                       u16* __restrict__ hlh, u16* __restrict__ hll,
                       u32* __restrict__ ctrl) {
  int i = blockIdx.x * 256 + threadIdx.x;
  if (i < 2 * BHE) {
    const int L = i >> 14, b = (i >> 9) & 31, hidx = i & 511;
    const int c = b >> 4, bl = b & 15, pid = L * 2 + c;
    float v = h0[i]; u16 hi = f2bf(v);
    hlh[pid * 16384 + bl * 512 + hidx] = hi;
    hll[pid * 16384 + bl * 512 + hidx] = f2bf(v - bf2f(hi));
  }
  if (i < 400) ctrl[i] = 0;   // intra[4][32] | xflag[4][32] | ictr[4] | ready | gmask | podxcc[128]
}

// ---- persistent pod scan ----
// 4 pods = (layer x batch-half), 32 WGs each, grouped by blockIdx%8 (R8-proven XCD-local).
// R10 = R8 + ONE change: intra-pod sync via L2-scope atomic counter (ictr); cross-pod
// flags stay on R8's proven agent-atomic per-WG array. Slow mode = R8 verbatim.
__global__ __launch_bounds__(NT, 2) void k_scan(
    const u16* __restrict__ WH0, const u16* __restrict__ WL0,
    const u16* __restrict__ WH1, const u16* __restrict__ WL1,
    const float* __restrict__ bsum0, const float* __restrict__ bsum1,
    const u16* __restrict__ xh, const u16* __restrict__ xl,
    u16* __restrict__ y0xh, u16* __restrict__ y0xl,   // [2][RING][16][512]
    u16* __restrict__ hlh, u16* __restrict__ hll,     // [4][2][16][512]
    const float* __restrict__ c0, float* __restrict__ out,
    u32* __restrict__ ctrl) {
  const int g = blockIdx.x & 7;
  if (g >= 4) return;                      // groups 4-7 idle out
  const int r = blockIdx.x >> 3;           // role 0..31 within pod
  const int pid = g, layer = g >> 1, c = g & 1;

  __shared__ f32x4 red[8][4][64];          // 32 KiB
  __shared__ int sh_fast;

  const int tid = threadIdx.x, ln = tid & 63, wv = tid >> 6;
  const int l15 = ln & 15, l16 = ln >> 4, koff = l16 * 8;

  u32* intra  = ctrl + pid * 32;                 // per-WG flags (slow mode only)
  u32* xflag  = ctrl + 128 + pid * 32;           // cross-pod progress (agent scope, R8 mechanism)
  u32* othX   = ctrl + 128 + ((layer == 0) ? (2 + c) : c) * 32;  // L0: L1 flags (BP); L1: L0 flags
  u32* ictr   = ctrl + 256 + pid;                // pod-local step counter (fast mode, L2 atomics)
  u32* ready  = ctrl + 264;
  u32* gmask  = ctrl + 265;
  u32* podxcc = ctrl + 272;

  // ---- one-time: verify each pod's 32 WGs share an XCD (R6-R9-proven block) ----
  if (tid == 0) {
    u32 xcc = __builtin_amdgcn_s_getreg(XCC_GETREG_IMM) & 0xffu;
    atomicOr(gmask, 1u << (xcc & 31u));
    __hip_atomic_store(&podxcc[pid * 32 + r], xcc | 0x100u, __ATOMIC_RELEASE, __HIP_MEMORY_SCOPE_AGENT);
    __hip_atomic_fetch_add(ready, 1u, __ATOMIC_ACQ_REL, __HIP_MEMORY_SCOPE_AGENT);
    while (__hip_atomic_load(ready, __ATOMIC_ACQUIRE, __HIP_MEMORY_SCOPE_AGENT) < 128u)
      __builtin_amdgcn_s_sleep(8);
    u32 v0 = __hip_atomic_load(&podxcc[pid * 32], __ATOMIC_ACQUIRE, __HIP_MEMORY_SCOPE_AGENT);
    int agree = 1;
    for (int j = 1; j < 32; ++j)
      agree &= (__hip_atomic_load(&podxcc[pid * 32 + j], __ATOMIC_ACQUIRE, __HIP_MEMORY_SCOPE_AGENT) == v0);
    u32 gm = __hip_atomic_load(gmask, __ATOMIC_ACQUIRE, __HIP_MEMORY_SCOPE_AGENT);
    sh_fast = (agree && __popc(gm) >= 2) ? 1 : 0;
  }
  __syncthreads();
  const bool fast = sh_fast != 0;

  // ---- pin this wave's weight fragments (2-limb, 4 row-tiles x 4 k-frags = 128 VGPR) ----
  const u16* WHp = layer ? WH1 : WH0;
  const u16* WLp = layer ? WL1 : WL0;
  bf16x8 wh[4][4], wl[4][4];
#pragma unroll
  for (int rt = 0; rt < 4; ++rt) {
    const size_t row = (size_t)(r * 64 + rt * 16 + l15) << 10;
#pragma unroll
    for (int kk = 0; kk < 4; ++kk) {
      const size_t kpos = (size_t)wv * 128 + kk * 32 + koff;
      wh[rt][kk] = *(const bf16x8*)(WHp + row + kpos);
      wl[rt][kk] = *(const bf16x8*)(WLp + row + kpos);
    }
  }
#pragma unroll
  for (int rt = 0; rt < 4; ++rt)
#pragma unroll
    for (int kk = 0; kk < 4; ++kk)
      asm volatile("" : "+v"(wh[rt][kk]), "+v"(wl[rt][kk]));

  // finalize identity (waves 0-3 own row-tile rt = wv)
  const int hidx = r * 16 + (wv & 3) * 4 + l16;
  const int bglob = c * 16 + l15;
  const float* bsum = layer ? bsum1 : bsum0;
  f32x4 bias = *(const f32x4*)(bsum + hidx * 4);
  float creg = c0[layer * BHE + bglob * HH + hidx];

  u16* myhlh = hlh + pid * 16384;   // [slot2][bl16][hidx512]
  u16* myhll = hll + pid * 16384;
  u16* y0h = y0xh + c * (RING * 8192);
  u16* y0l = y0xl + c * (RING * 8192);
  float* hnp = out + (size_t)TT * BHE + (size_t)layer * BHE;
  float* cnp = out + (size_t)TT * BHE + 2 * BHE + (size_t)layer * BHE;

  for (int t = 0; t < TT; ++t) {
    bf16x8 pbh[4], pbl[4];

    // ---- phase A: L0 x prefetch (cached, read-only, flag-independent) ----
    if (layer == 0 && wv < 4) {
      const u16* p1 = xh + (size_t)t * BHE + (size_t)bglob * 512 + wv * 128 + koff;
      const u16* p2 = xl + (size_t)t * BHE + (size_t)bglob * 512 + wv * 128 + koff;
#pragma unroll
      for (int kk = 0; kk < 4; ++kk) {
        pbh[kk] = *(const bf16x8*)(p1 + kk * 32);
        pbl[kk] = *(const bf16x8*)(p2 + kk * 32);
      }
    }

    // ---- phase B: wave 0 polls. Fast: lane 0 polls pod counter via L2 atomic add-0.
    //      Slow: lanes 0-31 poll per-WG flags via agent atomics (R8 verbatim).
    //      Lanes 32-63: cross flags via agent atomics (R8 mechanism, targets unchanged). ----
    if (wv == 0) {
      const u32 tgtOwn = (u32)t;
      const int needO = (layer == 1) || (t >= 16);
      const u32 tgtO = (layer == 1) ? (u32)(t + 1) : (u32)(t - 15);
      for (;;) {
        int ok = 1;
        if (fast) {
          if (ln == 0) ok = (at_add0_ret_l2(ictr) >= 32u * tgtOwn);
        } else {
          if (ln < 32)
            ok = (__hip_atomic_load(&intra[ln], __ATOMIC_RELAXED, __HIP_MEMORY_SCOPE_AGENT) >= tgtOwn);
        }
        if (ln >= 32 && needO)
          ok = (__hip_atomic_load(&othX[ln - 32], __ATOMIC_RELAXED, __HIP_MEMORY_SCOPE_AGENT) >= tgtO);
        if (__all(ok)) break;
        __builtin_amdgcn_s_sleep(1);
      }
    }
    __syncthreads();   // barrier 1: flags satisfied -> state readable

    // ---- phase C: remaining B loads ----
    if (layer == 0) {
      if (wv >= 4) {   // L0 h-part: pod-local (L2 scope in fast mode)
        const size_t base = ((size_t)(t & 1) * 16 + l15) * 512 + (wv - 4) * 128 + koff;
#pragma unroll
        for (int kk = 0; kk < 4; ++kk) {
          const u16* ph = myhlh + base + kk * 32;
          const u16* pl = myhll + base + kk * 32;
          pbh[kk] = fast ? ld128_l2(ph) : ld128_sys(ph);
          pbl[kk] = fast ? ld128_l2(pl) : ld128_sys(pl);
        }
      }
    } else {
      if (wv < 4) {    // L1 x-part: y0x ring slot t+1 (cross-XCD, sys)
        const size_t base = ((size_t)((t + 1) & (RING - 1)) * 16 + l15) * 512 + wv * 128 + koff;
#pragma unroll
        for (int kk = 0; kk < 4; ++kk) {
          pbh[kk] = ld128_sys(y0h + base + kk * 32);
          pbl[kk] = ld128_sys(y0l + base + kk * 32);
        }
      } else {         // L1 h-part: pod-local
        const size_t base = ((size_t)(t & 1) * 16 + l15) * 512 + (wv - 4) * 128 + koff;
#pragma unroll
        for (int kk = 0; kk < 4; ++kk) {
          const u16* ph = myhlh + base + kk * 32;
          const u16* pl = myhll + base + kk * 32;
          pbh[kk] = fast ? ld128_l2(ph) : ld128_sys(ph);
          pbl[kk] = fast ? ld128_l2(pl) : ld128_sys(pl);
        }
      }
    }
    SCHED0();
    asm volatile("s_waitcnt vmcnt(0)" ::: "memory");   // all B fragments resident
    SCHED0();

    // ---- phase D: acc += Wh*Bh + Wh*Bl + Wl*Bh (48 MFMA, 4 indep chains) ----
    f32x4 a0 = {0.f, 0.f, 0.f, 0.f}, a1 = a0, a2 = a0, a3 = a0;
#pragma unroll
    for (int kk = 0; kk < 4; ++kk) {
      a0 = __builtin_amdgcn_mfma_f32_16x16x32_bf16(wh[0][kk], pbh[kk], a0, 0, 0, 0);
      a1 = __builtin_amdgcn_mfma_f32_16x16x32_bf16(wh[1][kk], pbh[kk], a1, 0, 0, 0);
      a2 = __builtin_amdgcn_mfma_f32_16x16x32_bf16(wh[2][kk], pbh[kk], a2, 0, 0, 0);
      a3 = __builtin_amdgcn_mfma_f32_16x16x32_bf16(wh[3][kk], pbh[kk], a3, 0, 0, 0);
      a0 = __builtin_amdgcn_mfma_f32_16x16x32_bf16(wh[0][kk], pbl[kk], a0, 0, 0, 0);
      a1 = __builtin_amdgcn_mfma_f32_16x16x32_bf16(wh[1][kk], pbl[kk], a1, 0, 0, 0);
      a2 = __builtin_amdgcn_mfma_f32_16x16x32_bf16(wh[2][kk], pbl[kk], a2, 0, 0, 0);
      a3 = __builtin_amdgcn_mfma_f32_16x16x32_bf16(wh[3][kk], pbl[kk], a3, 0, 0, 0);
      a0 = __builtin_amdgcn_mfma_f32_16x16x32_bf16(wl[0][kk], pbh[kk], a0, 0, 0, 0);
      a1 = __builtin_amdgcn_mfma_f32_16x16x32_bf16(wl[1][kk], pbh[kk], a1, 0, 0, 0);
      a2 = __builtin_amdgcn_mfma_f32_16x16x32_bf16(wl[2][kk], pbh[kk], a2, 0, 0, 0);
      a3 = __builtin_amdgcn_mfma_f32_16x16x32_bf16(wl[3][kk], pbh[kk], a3, 0, 0, 0);
    }

    // ---- phase E: cross-wave K reduce (plain LDS; __syncthreads handles lgkm) ----
    red[wv][0][ln] = a0; red[wv][1][ln] = a1; red[wv][2][ln] = a2; red[wv][3][ln] = a3;
    __syncthreads();   // barrier 2

    // ---- phase F: finalize (waves 0-3, row-tile = wv) ----
    if (wv < 4) {
      f32x4 s = red[0][wv][ln];
#pragma unroll
      for (int w2 = 1; w2 < 8; ++w2) s += red[w2][wv][ln];
      const float gi = s[0] + bias[0], gf = s[1] + bias[1];
      const float gg = s[2] + bias[2], go = s[3] + bias[3];
      const float iv = sigm(gi), fv = sigm(gf), gv = tanh_(gg), ov = sigm(go);
      creg = fv * creg + iv * gv;
      const float h = ov * tanh_(creg);
      const u16 hhi = f2bf(h), hlo = f2bf(h - bf2f(hhi));

      // pod-local h (pod-RELATIVE offset)
      const size_t lb = ((size_t)((t + 1) & 1) * 16 + l15) * 512 + hidx;
      if (fast) { st16_l2(myhlh + lb, hhi); st16_l2(myhll + lb, hlo); }
      else      { st16_sys(myhlh + lb, hhi); st16_sys(myhll + lb, hlo); }
      // cross-pod / output
      if (layer == 0) {
        const size_t xb = ((size_t)((t + 1) & (RING - 1)) * 16 + l15) * 512 + hidx;
        st16_sys(y0h + xb, hhi); st16_sys(y0l + xb, hlo);
      } else {
        out[(size_t)t * BHE + (size_t)bglob * 512 + hidx] = h;   // y1 fp32, cached
      }
      if (t == TT - 1) {
        hnp[bglob * 512 + hidx] = h;
        cnp[bglob * 512 + hidx] = creg;
      }
    }
    asm volatile("s_waitcnt vmcnt(0)" ::: "memory");   // every wave drains ALL its stores
    __syncthreads();                                    // barrier 3: whole WG drained

    // ---- phase G: publish. Fast: L2 atomic add on pod counter. Slow: R8 per-WG flag.
    //      Always: cross-pod xflag via agent atomic (R8 mechanism). ----
    if (tid == 0) {
      if (fast) at_add1_l2(ictr);
      else      __hip_atomic_store(&intra[r], (u32)(t + 1), __ATOMIC_RELAXED, __HIP_MEMORY_SCOPE_AGENT);
      __hip_atomic_store(&xflag[r], (u32)(t + 1), __ATOMIC_RELAXED, __HIP_MEMORY_SCOPE_AGENT);
    }
  }
}

extern "C" void kernel_launch(void* const* d_in, const int* in_sizes, int n_in,
                              void* d_out, int out_size, void* d_ws, size_t ws_size,
                              hipStream_t stream) {
  (void)in_sizes; (void)n_in; (void)out_size; (void)ws_size;
  const float* x    = (const float*)d_in[0];
  const float* h0   = (const float*)d_in[1];
  const float* c0   = (const float*)d_in[2];
  const float* Wih0 = (const float*)d_in[3];
  const float* Whh0 = (const float*)d_in[4];
  const float* bih0 = (const float*)d_in[5];
  const float* bhh0 = (const float*)d_in[6];
  const float* Wih1 = (const float*)d_in[7];
  const float* Whh1 = (const float*)d_in[8];
  const float* bih1 = (const float*)d_in[9];
  const float* bhh1 = (const float*)d_in[10];
  float* out = (float*)d_out;

  char* w = (char*)d_ws;
  size_t off = 0;
  auto alloc = [&](size_t bytes) { void* q = w + off; off += (bytes + 255) & ~(size_t)255; return q; };
  u16* xh    = (u16*)alloc((size_t)TT * BB * II * 2);   // 64 MiB
  u16* xl    = (u16*)alloc((size_t)TT * BB * II * 2);   // 64 MiB
  u16* WH0   = (u16*)alloc((size_t)2048 * 1024 * 2);    // 4 MiB
  u16* WL0   = (u16*)alloc((size_t)2048 * 1024 * 2);
  u16* WH1   = (u16*)alloc((size_t)2048 * 1024 * 2);
  u16* WL1   = (u16*)alloc((size_t)2048 * 1024 * 2);
  float* bsum0 = (float*)alloc(2048 * 4);
  float* bsum1 = (float*)alloc(2048 * 4);
  u16* y0xh  = (u16*)alloc((size_t)2 * RING * 8192 * 2);  // [2][16][16][512]
  u16* y0xl  = (u16*)alloc((size_t)2 * RING * 8192 * 2);
  u16* hlh   = (u16*)alloc((size_t)4 * 16384 * 2);        // [4][2][16][512]
  u16* hll   = (u16*)alloc((size_t)4 * 16384 * 2);
  u32* ctrl  = (u32*)alloc(2048);

  k_cvt_x<<<dim3(2048), dim3(256), 0, stream>>>(x, xh, xl);
  k_build_w<<<dim3(4096), dim3(256), 0, stream>>>(Wih0, Whh0, bih0, bhh0,
                                                  Wih1, Whh1, bih1, bhh1,
                                                  WH0, WL0, WH1, WL1, bsum0, bsum1);
  k_init<<<dim3(128), dim3(256), 0, stream>>>(h0, hlh, hll, ctrl);
  k_scan<<<dim3(256), dim3(NT), 0, stream>>>(WH0, WL0, WH1, WL1, bsum0, bsum1,
                                             xh, xl, y0xh, y0xl, hlh, hll,
                                             c0, out, ctrl);
}

// Round 11
// 9552.604 us; speedup vs baseline: 1.1479x; 1.1479x over previous
//
#include <hip/hip_runtime.h>
#include <stdint.h>

#define TT 2048
#define BB 32
#define II 512
#define HH 512
#define BHE (BB * HH)      // 16384
#define NT 512             // 8 waves per WG
#define RING 16            // y0 cross-layer ring slots
#define XCC_GETREG_IMM (20 | (31 << 11))   // hwreg(HW_REG_XCC_ID=20, off 0, size 32)

typedef unsigned short u16;
typedef unsigned int u32;
typedef __attribute__((ext_vector_type(8))) short bf16x8;
typedef __attribute__((ext_vector_type(4))) float f32x4;

__device__ __forceinline__ u16 f2bf(float f) {
  u32 u = __float_as_uint(f);
  return (u16)((u + 0x7fffu + ((u >> 16) & 1u)) >> 16);  // RNE
}
__device__ __forceinline__ float bf2f(u16 h) { return __uint_as_float(((u32)h) << 16); }
__device__ __forceinline__ float sigm(float x) { return 1.f / (1.f + __expf(-x)); }
__device__ __forceinline__ float tanh_(float x) {
  float xc = fminf(fmaxf(x, -15.f), 15.f);
  float e = __expf(-2.f * xc);
  return (1.f - e) / (1.f + e);
}

// Data-path scope primitives. L2 (same-XCD): sc0. SYS (cross-XCD via MALL): sc0 sc1.
// (R8-proven: pods are XCD-local; L2-scope pod DATA communication is correct --
// data lines turn over in L1 every step. Flags must NOT use plain sc0 LOADS:
// a hot flag line can sit stale in L1 forever (R7/R9 deadlocks). Atomics bypass L1
// (R10-proven); R10's slowdown was single-line RMW serialization, fixed here by
// padding each WG's flag to its own 128B cacheline.)
__device__ __forceinline__ bf16x8 ld128_l2(const u16* p) {
  bf16x8 r; asm volatile("global_load_dwordx4 %0, %1, off sc0" : "=v"(r) : "v"(p) : "memory"); return r;
}
__device__ __forceinline__ bf16x8 ld128_sys(const u16* p) {
  bf16x8 r; asm volatile("global_load_dwordx4 %0, %1, off sc0 sc1" : "=v"(r) : "v"(p) : "memory"); return r;
}
__device__ __forceinline__ void st16_l2(u16* p, u16 v) {
  u32 vv = v; asm volatile("global_store_short %0, %1, off sc0" :: "v"(p), "v"(vv) : "memory");
}
__device__ __forceinline__ void st16_sys(u16* p, u16 v) {
  u32 vv = v; asm volatile("global_store_short %0, %1, off sc0 sc1" :: "v"(p), "v"(vv) : "memory");
}
// L2-scope flag primitives via ATOMICS (execute at L2, structurally bypass L1).
// Poll: atomic add-0 with return (sc0 = return-old), s_waitcnt EMBEDDED (R6 lesson).
__device__ __forceinline__ u32 at_add0_ret_l2(u32* p) {
  u32 r, z = 0;
  asm volatile("global_atomic_add %0, %1, %2, off sc0\n\ts_waitcnt vmcnt(0)"
               : "=v"(r) : "v"(p), "v"(z) : "memory");
  return r;
}
__device__ __forceinline__ void at_add1_l2(u32* p) {
  u32 one = 1;
  asm volatile("global_atomic_add %0, %1, off" :: "v"(p), "v"(one) : "memory");
}

#define SCHED0() __builtin_amdgcn_sched_barrier(0)

// ---- prep: x fp32 -> 2-limb bf16 ----
__global__ void k_cvt_x(const float* __restrict__ x, u16* __restrict__ xh, u16* __restrict__ xl) {
  const long n = (long)TT * BB * II;
  long i = ((long)blockIdx.x * 256 + threadIdx.x) * 4;
  const long stride = (long)gridDim.x * 256 * 4;
  for (; i < n; i += stride) {
    float4 v = *(const float4*)(x + i);
    ushort4 h, l;
    h.x = f2bf(v.x); l.x = f2bf(v.x - bf2f(h.x));
    h.y = f2bf(v.y); l.y = f2bf(v.y - bf2f(h.y));
    h.z = f2bf(v.z); l.z = f2bf(v.z - bf2f(h.z));
    h.w = f2bf(v.w); l.w = f2bf(v.w - bf2f(h.w));
    *(ushort4*)(xh + i) = h;
    *(ushort4*)(xl + i) = l;
  }
}

// ---- prep: gate-permuted 2-limb weights. rr = hidx*4+q, srow = q*512+hidx ----
__global__ void k_build_w(const float* __restrict__ Wih0, const float* __restrict__ Whh0,
                          const float* __restrict__ bih0, const float* __restrict__ bhh0,
                          const float* __restrict__ Wih1, const float* __restrict__ Whh1,
                          const float* __restrict__ bih1, const float* __restrict__ bhh1,
                          u16* __restrict__ WH0, u16* __restrict__ WL0,
                          u16* __restrict__ WH1, u16* __restrict__ WL1,
                          float* __restrict__ bsum0, float* __restrict__ bsum1) {
  const int rr = blockIdx.x & 2047;
  const int layer = blockIdx.x >> 11;
  const float* Wih = layer ? Wih1 : Wih0;
  const float* Whh = layer ? Whh1 : Whh0;
  u16* WH = (layer ? WH1 : WH0) + ((size_t)rr << 10);
  u16* WL = (layer ? WL1 : WL0) + ((size_t)rr << 10);
  const int hidx = rr >> 2, q = rr & 3;
  const int srow = q * HH + hidx;
  const float* si = Wih + (size_t)srow * II;
  const float* sh = Whh + (size_t)srow * HH;
  for (int k = threadIdx.x; k < 512; k += 256) {
    float wi = si[k]; u16 a = f2bf(wi); WH[k] = a;       WL[k] = f2bf(wi - bf2f(a));
    float wh = sh[k]; u16 b = f2bf(wh); WH[512 + k] = b; WL[512 + k] = f2bf(wh - bf2f(b));
  }
  if (threadIdx.x == 0)
    (layer ? bsum1 : bsum0)[rr] = (layer ? bih1 : bih0)[srow] + (layer ? bhh1 : bhh0)[srow];
}

// ---- prep: h0 -> per-pod hloc slot0 (2-limb), zero control block ----
// hloc layout: [pid][slot2][bl16][hidx512], pid = layer*2 + batchhalf
__global__ void k_init(const float* __restrict__ h0,
                       u16* __restrict__ hlh, u16* __restrict__ hll,
                       u32* __restrict__ ctrl) {
  int i = blockIdx.x * 256 + threadIdx.x;
  if (i < 2 * BHE) {
    const int L = i >> 14, b = (i >> 9) & 31, hidx = i & 511;
    const int c = b >> 4, bl = b & 15, pid = L * 2 + c;
    float v = h0[i]; u16 hi = f2bf(v);
    hlh[pid * 16384 + bl * 512 + hidx] = hi;
    hll[pid * 16384 + bl * 512 + hidx] = f2bf(v - bf2f(hi));
  }
  if (i < 4608) ctrl[i] = 0;   // ipad[4][32][32] | intra[4][32] | xflag[4][32] | ready | gmask | podxcc
}

// ---- persistent pod scan ----
// 4 pods = (layer x batch-half), 32 WGs each, grouped by blockIdx%8 (R8-proven XCD-local).
// R11 = R8 + ONE change: intra-pod flags = per-WG cacheline-padded words, published with
// L2 atomic add(+1), polled with 32 parallel L2 atomic add(+0,ret). Cross-pod flags and
// all barriers/drains identical to R8. Slow mode = R8 verbatim.
__global__ __launch_bounds__(NT, 2) void k_scan(
    const u16* __restrict__ WH0, const u16* __restrict__ WL0,
    const u16* __restrict__ WH1, const u16* __restrict__ WL1,
    const float* __restrict__ bsum0, const float* __restrict__ bsum1,
    const u16* __restrict__ xh, const u16* __restrict__ xl,
    u16* __restrict__ y0xh, u16* __restrict__ y0xl,   // [2][RING][16][512]
    u16* __restrict__ hlh, u16* __restrict__ hll,     // [4][2][16][512]
    const float* __restrict__ c0, float* __restrict__ out,
    u32* __restrict__ ctrl) {
  const int g = blockIdx.x & 7;
  if (g >= 4) return;                      // groups 4-7 idle out
  const int r = blockIdx.x >> 3;           // role 0..31 within pod
  const int pid = g, layer = g >> 1, c = g & 1;

  __shared__ f32x4 red[8][4][64];          // 32 KiB
  __shared__ int sh_fast;

  const int tid = threadIdx.x, ln = tid & 63, wv = tid >> 6;
  const int l15 = ln & 15, l16 = ln >> 4, koff = l16 * 8;

  u32* ipad   = ctrl + pid * 1024;               // fast intra flags: [wg]*32 (one line each)
  u32* intra  = ctrl + 4096 + pid * 32;          // slow-mode per-WG flags (R8)
  u32* xflag  = ctrl + 4224 + pid * 32;          // cross-pod progress (agent scope, R8)
  u32* othX   = ctrl + 4224 + ((layer == 0) ? (2 + c) : c) * 32;  // L0: L1 flags (BP); L1: L0 flags
  u32* ready  = ctrl + 4352;
  u32* gmask  = ctrl + 4353;
  u32* podxcc = ctrl + 4360;

  // ---- one-time: verify each pod's 32 WGs share an XCD (R6-R10-proven block) ----
  if (tid == 0) {
    u32 xcc = __builtin_amdgcn_s_getreg(XCC_GETREG_IMM) & 0xffu;
    atomicOr(gmask, 1u << (xcc & 31u));
    __hip_atomic_store(&podxcc[pid * 32 + r], xcc | 0x100u, __ATOMIC_RELEASE, __HIP_MEMORY_SCOPE_AGENT);
    __hip_atomic_fetch_add(ready, 1u, __ATOMIC_ACQ_REL, __HIP_MEMORY_SCOPE_AGENT);
    while (__hip_atomic_load(ready, __ATOMIC_ACQUIRE, __HIP_MEMORY_SCOPE_AGENT) < 128u)
      __builtin_amdgcn_s_sleep(8);
    u32 v0 = __hip_atomic_load(&podxcc[pid * 32], __ATOMIC_ACQUIRE, __HIP_MEMORY_SCOPE_AGENT);
    int agree = 1;
    for (int j = 1; j < 32; ++j)
      agree &= (__hip_atomic_load(&podxcc[pid * 32 + j], __ATOMIC_ACQUIRE, __HIP_MEMORY_SCOPE_AGENT) == v0);
    u32 gm = __hip_atomic_load(gmask, __ATOMIC_ACQUIRE, __HIP_MEMORY_SCOPE_AGENT);
    sh_fast = (agree && __popc(gm) >= 2) ? 1 : 0;
  }
  __syncthreads();
  const bool fast = sh_fast != 0;

  // ---- pin this wave's weight fragments (2-limb, 4 row-tiles x 4 k-frags = 128 VGPR) ----
  const u16* WHp = layer ? WH1 : WH0;
  const u16* WLp = layer ? WL1 : WL0;
  bf16x8 wh[4][4], wl[4][4];
#pragma unroll
  for (int rt = 0; rt < 4; ++rt) {
    const size_t row = (size_t)(r * 64 + rt * 16 + l15) << 10;
#pragma unroll
    for (int kk = 0; kk < 4; ++kk) {
      const size_t kpos = (size_t)wv * 128 + kk * 32 + koff;
      wh[rt][kk] = *(const bf16x8*)(WHp + row + kpos);
      wl[rt][kk] = *(const bf16x8*)(WLp + row + kpos);
    }
  }
#pragma unroll
  for (int rt = 0; rt < 4; ++rt)
#pragma unroll
    for (int kk = 0; kk < 4; ++kk)
      asm volatile("" : "+v"(wh[rt][kk]), "+v"(wl[rt][kk]));

  // finalize identity (waves 0-3 own row-tile rt = wv)
  const int hidx = r * 16 + (wv & 3) * 4 + l16;
  const int bglob = c * 16 + l15;
  const float* bsum = layer ? bsum1 : bsum0;
  f32x4 bias = *(const f32x4*)(bsum + hidx * 4);
  float creg = c0[layer * BHE + bglob * HH + hidx];

  u16* myhlh = hlh + pid * 16384;   // [slot2][bl16][hidx512]
  u16* myhll = hll + pid * 16384;
  u16* y0h = y0xh + c * (RING * 8192);
  u16* y0l = y0xl + c * (RING * 8192);
  float* hnp = out + (size_t)TT * BHE + (size_t)layer * BHE;
  float* cnp = out + (size_t)TT * BHE + 2 * BHE + (size_t)layer * BHE;

  for (int t = 0; t < TT; ++t) {
    bf16x8 pbh[4], pbl[4];

    // ---- phase A: L0 x prefetch (cached, read-only, flag-independent) ----
    if (layer == 0 && wv < 4) {
      const u16* p1 = xh + (size_t)t * BHE + (size_t)bglob * 512 + wv * 128 + koff;
      const u16* p2 = xl + (size_t)t * BHE + (size_t)bglob * 512 + wv * 128 + koff;
#pragma unroll
      for (int kk = 0; kk < 4; ++kk) {
        pbh[kk] = *(const bf16x8*)(p1 + kk * 32);
        pbl[kk] = *(const bf16x8*)(p2 + kk * 32);
      }
    }

    // ---- phase B: wave 0 polls. Fast: lanes 0-31 poll padded per-WG flags via parallel
    //      L2 atomic add-0 (distinct cachelines). Slow: R8 agent-atomic flags.
    //      Lanes 32-63: cross flags via agent atomics (R8 mechanism, targets unchanged). ----
    if (wv == 0) {
      const u32 tgtOwn = (u32)t;
      const int needO = (layer == 1) || (t >= 16);
      const u32 tgtO = (layer == 1) ? (u32)(t + 1) : (u32)(t - 15);
      for (;;) {
        int ok = 1;
        if (ln < 32) {
          u32 f = fast ? at_add0_ret_l2(&ipad[ln * 32])
                       : __hip_atomic_load(&intra[ln], __ATOMIC_RELAXED, __HIP_MEMORY_SCOPE_AGENT);
          ok = (f >= tgtOwn);
        } else if (needO) {
          ok = (__hip_atomic_load(&othX[ln - 32], __ATOMIC_RELAXED, __HIP_MEMORY_SCOPE_AGENT) >= tgtO);
        }
        if (__all(ok)) break;
        __builtin_amdgcn_s_sleep(1);
      }
    }
    __syncthreads();   // barrier 1: flags satisfied -> state readable

    // ---- phase C: remaining B loads ----
    if (layer == 0) {
      if (wv >= 4) {   // L0 h-part: pod-local (L2 scope in fast mode)
        const size_t base = ((size_t)(t & 1) * 16 + l15) * 512 + (wv - 4) * 128 + koff;
#pragma unroll
        for (int kk = 0; kk < 4; ++kk) {
          const u16* ph = myhlh + base + kk * 32;
          const u16* pl = myhll + base + kk * 32;
          pbh[kk] = fast ? ld128_l2(ph) : ld128_sys(ph);
          pbl[kk] = fast ? ld128_l2(pl) : ld128_sys(pl);
        }
      }
    } else {
      if (wv < 4) {    // L1 x-part: y0x ring slot t+1 (cross-XCD, sys)
        const size_t base = ((size_t)((t + 1) & (RING - 1)) * 16 + l15) * 512 + wv * 128 + koff;
#pragma unroll
        for (int kk = 0; kk < 4; ++kk) {
          pbh[kk] = ld128_sys(y0h + base + kk * 32);
          pbl[kk] = ld128_sys(y0l + base + kk * 32);
        }
      } else {         // L1 h-part: pod-local
        const size_t base = ((size_t)(t & 1) * 16 + l15) * 512 + (wv - 4) * 128 + koff;
#pragma unroll
        for (int kk = 0; kk < 4; ++kk) {
          const u16* ph = myhlh + base + kk * 32;
          const u16* pl = myhll + base + kk * 32;
          pbh[kk] = fast ? ld128_l2(ph) : ld128_sys(ph);
          pbl[kk] = fast ? ld128_l2(pl) : ld128_sys(pl);
        }
      }
    }
    SCHED0();
    asm volatile("s_waitcnt vmcnt(0)" ::: "memory");   // all B fragments resident
    SCHED0();

    // ---- phase D: acc += Wh*Bh + Wh*Bl + Wl*Bh (48 MFMA, 4 indep chains) ----
    f32x4 a0 = {0.f, 0.f, 0.f, 0.f}, a1 = a0, a2 = a0, a3 = a0;
#pragma unroll
    for (int kk = 0; kk < 4; ++kk) {
      a0 = __builtin_amdgcn_mfma_f32_16x16x32_bf16(wh[0][kk], pbh[kk], a0, 0, 0, 0);
      a1 = __builtin_amdgcn_mfma_f32_16x16x32_bf16(wh[1][kk], pbh[kk], a1, 0, 0, 0);
      a2 = __builtin_amdgcn_mfma_f32_16x16x32_bf16(wh[2][kk], pbh[kk], a2, 0, 0, 0);
      a3 = __builtin_amdgcn_mfma_f32_16x16x32_bf16(wh[3][kk], pbh[kk], a3, 0, 0, 0);
      a0 = __builtin_amdgcn_mfma_f32_16x16x32_bf16(wh[0][kk], pbl[kk], a0, 0, 0, 0);
      a1 = __builtin_amdgcn_mfma_f32_16x16x32_bf16(wh[1][kk], pbl[kk], a1, 0, 0, 0);
      a2 = __builtin_amdgcn_mfma_f32_16x16x32_bf16(wh[2][kk], pbl[kk], a2, 0, 0, 0);
      a3 = __builtin_amdgcn_mfma_f32_16x16x32_bf16(wh[3][kk], pbl[kk], a3, 0, 0, 0);
      a0 = __builtin_amdgcn_mfma_f32_16x16x32_bf16(wl[0][kk], pbh[kk], a0, 0, 0, 0);
      a1 = __builtin_amdgcn_mfma_f32_16x16x32_bf16(wl[1][kk], pbh[kk], a1, 0, 0, 0);
      a2 = __builtin_amdgcn_mfma_f32_16x16x32_bf16(wl[2][kk], pbh[kk], a2, 0, 0, 0);
      a3 = __builtin_amdgcn_mfma_f32_16x16x32_bf16(wl[3][kk], pbh[kk], a3, 0, 0, 0);
    }

    // ---- phase E: cross-wave K reduce (plain LDS; __syncthreads handles lgkm) ----
    red[wv][0][ln] = a0; red[wv][1][ln] = a1; red[wv][2][ln] = a2; red[wv][3][ln] = a3;
    __syncthreads();   // barrier 2

    // ---- phase F: finalize (waves 0-3, row-tile = wv) ----
    if (wv < 4) {
      f32x4 s = red[0][wv][ln];
#pragma unroll
      for (int w2 = 1; w2 < 8; ++w2) s += red[w2][wv][ln];
      const float gi = s[0] + bias[0], gf = s[1] + bias[1];
      const float gg = s[2] + bias[2], go = s[3] + bias[3];
      const float iv = sigm(gi), fv = sigm(gf), gv = tanh_(gg), ov = sigm(go);
      creg = fv * creg + iv * gv;
      const float h = ov * tanh_(creg);
      const u16 hhi = f2bf(h), hlo = f2bf(h - bf2f(hhi));

      // pod-local h (pod-RELATIVE offset)
      const size_t lb = ((size_t)((t + 1) & 1) * 16 + l15) * 512 + hidx;
      if (fast) { st16_l2(myhlh + lb, hhi); st16_l2(myhll + lb, hlo); }
      else      { st16_sys(myhlh + lb, hhi); st16_sys(myhll + lb, hlo); }
      // cross-pod / output
      if (layer == 0) {
        const size_t xb = ((size_t)((t + 1) & (RING - 1)) * 16 + l15) * 512 + hidx;
        st16_sys(y0h + xb, hhi); st16_sys(y0l + xb, hlo);
      } else {
        out[(size_t)t * BHE + (size_t)bglob * 512 + hidx] = h;   // y1 fp32, cached
      }
      if (t == TT - 1) {
        hnp[bglob * 512 + hidx] = h;
        cnp[bglob * 512 + hidx] = creg;
      }
    }
    asm volatile("s_waitcnt vmcnt(0)" ::: "memory");   // every wave drains ALL its stores
    __syncthreads();                                    // barrier 3: whole WG drained

    // ---- phase G: publish. Fast: L2 atomic +1 on own padded flag (value = steps done).
    //      Slow: R8 per-WG agent flag. Always: cross-pod xflag via agent atomic. ----
    if (tid == 0) {
      if (fast) at_add1_l2(&ipad[r * 32]);
      else      __hip_atomic_store(&intra[r], (u32)(t + 1), __ATOMIC_RELAXED, __HIP_MEMORY_SCOPE_AGENT);
      __hip_atomic_store(&xflag[r], (u32)(t + 1), __ATOMIC_RELAXED, __HIP_MEMORY_SCOPE_AGENT);
    }
  }
}

extern "C" void kernel_launch(void* const* d_in, const int* in_sizes, int n_in,
                              void* d_out, int out_size, void* d_ws, size_t ws_size,
                              hipStream_t stream) {
  (void)in_sizes; (void)n_in; (void)out_size; (void)ws_size;
  const float* x    = (const float*)d_in[0];
  const float* h0   = (const float*)d_in[1];
  const float* c0   = (const float*)d_in[2];
  const float* Wih0 = (const float*)d_in[3];
  const float* Whh0 = (const float*)d_in[4];
  const float* bih0 = (const float*)d_in[5];
  const float* bhh0 = (const float*)d_in[6];
  const float* Wih1 = (const float*)d_in[7];
  const float* Whh1 = (const float*)d_in[8];
  const float* bih1 = (const float*)d_in[9];
  const float* bhh1 = (const float*)d_in[10];
  float* out = (float*)d_out;

  char* w = (char*)d_ws;
  size_t off = 0;
  auto alloc = [&](size_t bytes) { void* q = w + off; off += (bytes + 255) & ~(size_t)255; return q; };
  u16* xh    = (u16*)alloc((size_t)TT * BB * II * 2);   // 64 MiB
  u16* xl    = (u16*)alloc((size_t)TT * BB * II * 2);   // 64 MiB
  u16* WH0   = (u16*)alloc((size_t)2048 * 1024 * 2);    // 4 MiB
  u16* WL0   = (u16*)alloc((size_t)2048 * 1024 * 2);
  u16* WH1   = (u16*)alloc((size_t)2048 * 1024 * 2);
  u16* WL1   = (u16*)alloc((size_t)2048 * 1024 * 2);
  float* bsum0 = (float*)alloc(2048 * 4);
  float* bsum1 = (float*)alloc(2048 * 4);
  u16* y0xh  = (u16*)alloc((size_t)2 * RING * 8192 * 2);  // [2][16][16][512]
  u16* y0xl  = (u16*)alloc((size_t)2 * RING * 8192 * 2);
  u16* hlh   = (u16*)alloc((size_t)4 * 16384 * 2);        // [4][2][16][512]
  u16* hll   = (u16*)alloc((size_t)4 * 16384 * 2);
  u32* ctrl  = (u32*)alloc(32768);                        // padded flags + control

  k_cvt_x<<<dim3(2048), dim3(256), 0, stream>>>(x, xh, xl);
  k_build_w<<<dim3(4096), dim3(256), 0, stream>>>(Wih0, Whh0, bih0, bhh0,
                                                  Wih1, Whh1, bih1, bhh1,
                                                  WH0, WL0, WH1, WL1, bsum0, bsum1);
  k_init<<<dim3(128), dim3(256), 0, stream>>>(h0, hlh, hll, ctrl);
  k_scan<<<dim3(256), dim3(NT), 0, stream>>>(WH0, WL0, WH1, WL1, bsum0, bsum1,
                                             xh, xl, y0xh, y0xl, hlh, hll,
                                             c0, out, ctrl);
}